// Round 4
// baseline (231.084 us; speedup 1.0000x reference)
//
#include <hip/hip_runtime.h>
#include <math.h>

#define NELEM 1048576    // B*C*H*W
#define CHW 32768
#define TILE 256         // elements per block
#define NBLK (NELEM / TILE)   // 4096
#define LOG2E 1.44269504088896340736f
#define LN2   0.69314718055994530942f

typedef const __attribute__((address_space(1))) void g_void;
typedef __attribute__((address_space(3))) void l_void;

__global__ void init_sldj_kernel(const float* __restrict__ sldj,
                                 float* __restrict__ out_sldj, int B) {
    int i = blockIdx.x * blockDim.x + threadIdx.x;
    if (i < B) out_sldj[i] = sldj[i];
}

// Stage pi/mu/s (48 KB / 256-element tile) into LDS via global_load_lds DMA,
// then compute with 4 lanes per element (conflict-free ds_read_b128).
__global__ __launch_bounds__(256) void coupling_kernel(
    const float* __restrict__ x_change, const float* __restrict__ x_id,
    const float* __restrict__ a, const float* __restrict__ b,
    const float* __restrict__ pi, const float* __restrict__ mu,
    const float* __restrict__ s, float* __restrict__ out) {
    __shared__ __align__(16) float ldsP[TILE * 16];
    __shared__ __align__(16) float ldsM[TILE * 16];
    __shared__ __align__(16) float ldsS[TILE * 16];

    const int t = threadIdx.x;
    const int w = t >> 6;          // wave 0..3
    const int l = t & 63;          // lane
    const int e0 = blockIdx.x * TILE;

    // ---- async DMA: each wave stages 4 KB per array (4 chunks x 1 KB) ----
    {
        const size_t gbase = (size_t)e0 * 16 + (size_t)(w * 1024 + l * 4);
        const int lbase = w * 1024 + l * 4;
#pragma unroll
        for (int c = 0; c < 4; ++c) {
            __builtin_amdgcn_global_load_lds((g_void*)(pi + gbase + c * 256),
                                             (l_void*)(ldsP + lbase + c * 256), 16, 0, 0);
            __builtin_amdgcn_global_load_lds((g_void*)(mu + gbase + c * 256),
                                             (l_void*)(ldsM + lbase + c * 256), 16, 0, 0);
            __builtin_amdgcn_global_load_lds((g_void*)(s + gbase + c * 256),
                                             (l_void*)(ldsS + lbase + c * 256), 16, 0, 0);
        }
    }

    // ---- small direct loads overlap the DMA ----
    const int kq = t & 3;          // component-quad owned by this lane
    const int g = t >> 2;          // element group (0..63)
    float xv[4], av[4], bv[4];
#pragma unroll
    for (int p = 0; p < 4; ++p) {
        const int e = e0 + p * 64 + g;
        xv[p] = x_change[e];
        av[p] = a[e];
        bv[p] = b[e];
    }
    out[(size_t)NELEM + e0 + t] = x_id[e0 + t];   // identity passthrough

    __builtin_amdgcn_s_waitcnt(0);                 // drain DMA before barrier
    __syncthreads();

    // ---- compute: 4 passes of 64 elements; lane handles 4 components ----
    float ldj = 0.0f;
    const float4* P4 = (const float4*)ldsP;
    const float4* M4 = (const float4*)ldsM;
    const float4* S4 = (const float4*)ldsS;
#pragma unroll
    for (int p = 0; p < 4; ++p) {
        const int idx = (p * 64 + g) * 4 + kq;     // contiguous across lanes
        const float4 pv = P4[idx];
        const float4 mv = M4[idx];
        const float4 sv = S4[idx];
        const float x = xv[p];

        float psum = 0.0f, cdf = 0.0f, omu = 0.0f, pdf = 0.0f;
        const float pk[4] = {pv.x, pv.y, pv.z, pv.w};
        const float mk[4] = {mv.x, mv.y, mv.z, mv.w};
        const float sk[4] = {sv.x, sv.y, sv.z, sv.w};
#pragma unroll
        for (int j = 0; j < 4; ++j) {
            const float wk = __builtin_amdgcn_exp2f(pk[j] * LOG2E);   // e^pi (unnormalized; pi~N(0,1) safe)
            const float ez = __builtin_amdgcn_exp2f(-sk[j] * LOG2E);  // e^{-s}
            const float z = (x - mk[j]) * ez;
            const float enz = __builtin_amdgcn_exp2f(-z * LOG2E);     // e^{-z}
            const float gg = __builtin_amdgcn_rcpf(1.0f + enz);       // sigmoid(z)
            const float wg = wk * gg;
            psum += wk;                    // Σ w
            cdf += wg;                     // Σ w·g
            omu += wg * enz;               // Σ w·(1-g)
            pdf += wk * ez * gg * gg * enz;// Σ w·e^{-s}·g·(1-g)
        }
        psum += __shfl_xor(psum, 1); psum += __shfl_xor(psum, 2);
        cdf  += __shfl_xor(cdf, 1);  cdf  += __shfl_xor(cdf, 2);
        omu  += __shfl_xor(omu, 1);  omu  += __shfl_xor(omu, 2);
        pdf  += __shfl_xor(pdf, 1);  pdf  += __shfl_xor(pdf, 2);

        if (kq == 0) {
            const float l2psum = __builtin_amdgcn_logf(psum);
            const float l2cdf  = __builtin_amdgcn_logf(cdf);
            const float l2omu  = __builtin_amdgcn_logf(fmaxf(omu, 1e-38f));
            const float l2pdf  = __builtin_amdgcn_logf(fmaxf(pdf, 1e-38f));
            // out = (log_cdf - log(1-u) + b)*e^a ; psum cancels in the difference
            const float outv = (l2cdf - l2omu) * LN2;
            out[e0 + p * 64 + g] = (outv + bv[p]) * __builtin_amdgcn_exp2f(av[p] * LOG2E);
            // ldj = log_pdf - log_cdf - log(1-u) + a
            ldj += (l2pdf + l2psum - l2cdf - l2omu) * LN2 + av[p];
        }
    }

    // ---- block reduction; block (256 elems) lies within one batch ----
    float v = ldj;
#pragma unroll
    for (int off = 32; off > 0; off >>= 1) v += __shfl_down(v, off);
    __shared__ float ws[4];
    if ((t & 63) == 0) ws[w] = v;
    __syncthreads();
    if (t == 0) {
        const float tot = ws[0] + ws[1] + ws[2] + ws[3];
        const int batch = blockIdx.x >> 7;   // 128 blocks per batch
        atomicAdd(out + 2 * (size_t)NELEM + batch, tot);
    }
}

extern "C" void kernel_launch(void* const* d_in, const int* in_sizes, int n_in,
                              void* d_out, int out_size, void* d_ws, size_t ws_size,
                              hipStream_t stream) {
    const float* x_change = (const float*)d_in[0];
    const float* x_id     = (const float*)d_in[1];
    const float* sldj     = (const float*)d_in[2];
    const float* a        = (const float*)d_in[3];
    const float* b        = (const float*)d_in[4];
    const float* pi       = (const float*)d_in[5];
    const float* mu       = (const float*)d_in[6];
    const float* s        = (const float*)d_in[7];
    float* out = (float*)d_out;

    const int B = in_sizes[2];

    init_sldj_kernel<<<1, 64, 0, stream>>>(sldj, out + 2 * (size_t)NELEM, B);
    coupling_kernel<<<NBLK, 256, 0, stream>>>(x_change, x_id, a, b, pi, mu, s, out);
}

// Round 5
// 222.529 us; speedup vs baseline: 1.0384x; 1.0384x over previous
//
#include <hip/hip_runtime.h>
#include <math.h>

#define NELEM 1048576    // B*C*H*W
#define NBLK 2048        // 8 blocks/CU on 256 CUs
#define ITERS 8          // 64 elements per iter -> 512 elements per block
#define LOG2E 1.44269504088896340736f
#define LN2   0.69314718055994530942f

// 4 lanes per element (one float4 of pi/mu/s each), register-pipelined:
// iteration i issues iteration i+1's loads before computing on i.
__global__ __launch_bounds__(256, 7) void coupling_kernel(
    const float* __restrict__ x_change, const float* __restrict__ x_id,
    const float* __restrict__ a, const float* __restrict__ b,
    const float4* __restrict__ pi4, const float4* __restrict__ mu4,
    const float4* __restrict__ s4, float* __restrict__ out) {
    const int t = threadIdx.x;
    const int kq = t & 3;          // component-quad owned by this lane
    const int g = t >> 2;          // element group 0..63
    const int e0 = blockIdx.x * (64 * ITERS);

    // identity passthrough: 512 floats per block, float4-coalesced, issued
    // first so it overlaps the pipeline fill.
    if (t < 128) {
        ((float4*)(out + NELEM + e0))[t] = ((const float4*)(x_id + e0))[t];
    }

    // ---- pipeline prologue ----
    int e = e0 + g;
    float4 P = pi4[(size_t)e * 4 + kq];
    float4 M = mu4[(size_t)e * 4 + kq];
    float4 S = s4[(size_t)e * 4 + kq];
    float x = x_change[e], av = a[e], bv = b[e];

    float ldj = 0.0f;

#pragma unroll 2
    for (int it = 0; it < ITERS; ++it) {
        // issue next iteration's loads (redundant re-load on last iter, cheap)
        const int en = (it + 1 < ITERS) ? (e + 64) : e;
        const float4 Pn = pi4[(size_t)en * 4 + kq];
        const float4 Mn = mu4[(size_t)en * 4 + kq];
        const float4 Sn = s4[(size_t)en * 4 + kq];
        const float xn = x_change[en], avn = a[en], bvn = b[en];

        // ---- compute current ----
        float psum = 0.0f, cdf = 0.0f, omu = 0.0f, pdf = 0.0f;
        {
            const float pk[4] = {P.x, P.y, P.z, P.w};
            const float mk[4] = {M.x, M.y, M.z, M.w};
            const float sk[4] = {S.x, S.y, S.z, S.w};
#pragma unroll
            for (int j = 0; j < 4; ++j) {
                const float wk = __builtin_amdgcn_exp2f(pk[j] * LOG2E);   // e^pi (pi~N(0,1), safe unnormalized)
                const float ez = __builtin_amdgcn_exp2f(-sk[j] * LOG2E);  // e^{-s}
                const float z = (x - mk[j]) * ez;
                const float enz = __builtin_amdgcn_exp2f(-z * LOG2E);     // e^{-z}
                const float gg = __builtin_amdgcn_rcpf(1.0f + enz);       // sigmoid(z)
                const float wg = wk * gg;
                psum += wk;                      // Σ w
                cdf += wg;                       // Σ w·g
                omu += wg * enz;                 // Σ w·(1-g)
                pdf += wk * ez * gg * gg * enz;  // Σ w·e^{-s}·g·(1-g)
            }
        }
        psum += __shfl_xor(psum, 1); psum += __shfl_xor(psum, 2);
        cdf  += __shfl_xor(cdf, 1);  cdf  += __shfl_xor(cdf, 2);
        omu  += __shfl_xor(omu, 1);  omu  += __shfl_xor(omu, 2);
        pdf  += __shfl_xor(pdf, 1);  pdf  += __shfl_xor(pdf, 2);

        if (kq == 0) {
            const float l2psum = __builtin_amdgcn_logf(psum);
            const float l2cdf  = __builtin_amdgcn_logf(cdf);
            const float l2omu  = __builtin_amdgcn_logf(fmaxf(omu, 1e-38f));
            const float l2pdf  = __builtin_amdgcn_logf(fmaxf(pdf, 1e-38f));
            // out = (log_cdf - log(1-u) + b)*e^a ; psum cancels in the diff
            out[e] = ((l2cdf - l2omu) * LN2 + bv) * __builtin_amdgcn_exp2f(av * LOG2E);
            // ldj = log_pdf - log_cdf - log(1-u) + a
            ldj += (l2pdf + l2psum - l2cdf - l2omu) * LN2 + av;
        }

        // ---- rotate pipeline ----
        P = Pn; M = Mn; S = Sn; x = xn; av = avn; bv = bvn; e = en;
    }

    // ---- block reduction; block (512 elems) lies within one batch ----
    float v = ldj;
#pragma unroll
    for (int off = 32; off > 0; off >>= 1) v += __shfl_down(v, off);
    __shared__ float ws[4];
    const int w = t >> 6;
    if ((t & 63) == 0) ws[w] = v;
    __syncthreads();
    if (t == 0) {
        const float tot = ws[0] + ws[1] + ws[2] + ws[3];
        const int batch = blockIdx.x >> 6;   // 64 blocks (512 elems each) per batch
        atomicAdd(out + 2 * (size_t)NELEM + batch, tot);
    }
}

extern "C" void kernel_launch(void* const* d_in, const int* in_sizes, int n_in,
                              void* d_out, int out_size, void* d_ws, size_t ws_size,
                              hipStream_t stream) {
    const float* x_change = (const float*)d_in[0];
    const float* x_id     = (const float*)d_in[1];
    const float* sldj     = (const float*)d_in[2];
    const float* a        = (const float*)d_in[3];
    const float* b        = (const float*)d_in[4];
    const float4* pi      = (const float4*)d_in[5];
    const float4* mu      = (const float4*)d_in[6];
    const float4* s       = (const float4*)d_in[7];
    float* out = (float*)d_out;

    const int B = in_sizes[2];

    // Seed sldj output region (harness poisons d_out) with a tiny d2d copy;
    // the kernel atomically accumulates into it (stream-ordered).
    hipMemcpyAsync(out + 2 * (size_t)NELEM, sldj, B * sizeof(float),
                   hipMemcpyDeviceToDevice, stream);

    coupling_kernel<<<NBLK, 256, 0, stream>>>(x_change, x_id, a, b, pi, mu, s, out);
}

// Round 6
// 212.642 us; speedup vs baseline: 1.0867x; 1.0465x over previous
//
#include <hip/hip_runtime.h>
#include <math.h>

#define NELEM 1048576    // B*C*H*W
#define NBLK 2048        // 8 blocks/CU on 256 CUs
#define ITERS 4          // 2 element-quads (128 elems) per iter -> 512 elems/block
#define LOG2E 1.44269504088896340736f
#define LN2   0.69314718055994530942f

typedef float f32x4 __attribute__((ext_vector_type(4)));

// 4 lanes per element; two elements in flight per iteration with all six
// 16B loads issued (nontemporal) before any consumer -> real in-register MLP.
__global__ __launch_bounds__(256) void coupling_kernel(
    const float* __restrict__ x_change, const float* __restrict__ x_id,
    const float* __restrict__ a, const float* __restrict__ b,
    const f32x4* __restrict__ pi4, const f32x4* __restrict__ mu4,
    const f32x4* __restrict__ s4, float* __restrict__ out) {
    const int t = threadIdx.x;
    const int kq = t & 3;          // component-quad owned by this lane
    const int g = t >> 2;          // element group 0..63
    const int e0 = blockIdx.x * 512;

    // identity passthrough, float4-coalesced, overlaps everything
    if (t < 128) {
        ((f32x4*)(out + NELEM + e0))[t] = ((const f32x4*)(x_id + e0))[t];
    }

    float ldj = 0.0f;
    for (int it = 0; it < ITERS; ++it) {
        const int eA = e0 + it * 128 + g;
        const int eB = eA + 64;
        const size_t iA = (size_t)eA * 4 + kq;
        const size_t iB = (size_t)eB * 4 + kq;

        // ---- 6 independent nontemporal 16B loads (batch-issued) ----
        const f32x4 PA = __builtin_nontemporal_load(pi4 + iA);
        const f32x4 MA = __builtin_nontemporal_load(mu4 + iA);
        const f32x4 SA = __builtin_nontemporal_load(s4 + iA);
        const f32x4 PB = __builtin_nontemporal_load(pi4 + iB);
        const f32x4 MB = __builtin_nontemporal_load(mu4 + iB);
        const f32x4 SB = __builtin_nontemporal_load(s4 + iB);
        const float xA = x_change[eA], aA = a[eA], bA = b[eA];
        const float xB = x_change[eB], aB = a[eB], bB = b[eB];

        float psA = 0.f, cdfA = 0.f, omuA = 0.f, pdfA = 0.f;
        float psB = 0.f, cdfB = 0.f, omuB = 0.f, pdfB = 0.f;
#pragma unroll
        for (int j = 0; j < 4; ++j) {
            {   // element A
                const float wk = __builtin_amdgcn_exp2f(PA[j] * LOG2E);
                const float ez = __builtin_amdgcn_exp2f(-SA[j] * LOG2E);
                const float z = (xA - MA[j]) * ez;
                const float enz = __builtin_amdgcn_exp2f(-z * LOG2E);
                const float gg = __builtin_amdgcn_rcpf(1.0f + enz);
                const float wg = wk * gg;
                psA += wk; cdfA += wg; omuA += wg * enz;
                pdfA += wk * ez * gg * gg * enz;
            }
            {   // element B (independent chain -> ILP)
                const float wk = __builtin_amdgcn_exp2f(PB[j] * LOG2E);
                const float ez = __builtin_amdgcn_exp2f(-SB[j] * LOG2E);
                const float z = (xB - MB[j]) * ez;
                const float enz = __builtin_amdgcn_exp2f(-z * LOG2E);
                const float gg = __builtin_amdgcn_rcpf(1.0f + enz);
                const float wg = wk * gg;
                psB += wk; cdfB += wg; omuB += wg * enz;
                pdfB += wk * ez * gg * gg * enz;
            }
        }
        psA += __shfl_xor(psA, 1); psA += __shfl_xor(psA, 2);
        cdfA += __shfl_xor(cdfA, 1); cdfA += __shfl_xor(cdfA, 2);
        omuA += __shfl_xor(omuA, 1); omuA += __shfl_xor(omuA, 2);
        pdfA += __shfl_xor(pdfA, 1); pdfA += __shfl_xor(pdfA, 2);
        psB += __shfl_xor(psB, 1); psB += __shfl_xor(psB, 2);
        cdfB += __shfl_xor(cdfB, 1); cdfB += __shfl_xor(cdfB, 2);
        omuB += __shfl_xor(omuB, 1); omuB += __shfl_xor(omuB, 2);
        pdfB += __shfl_xor(pdfB, 1); pdfB += __shfl_xor(pdfB, 2);

        if (kq == 0) {
            {   // element A epilogue
                const float l2ps = __builtin_amdgcn_logf(psA);
                const float l2c  = __builtin_amdgcn_logf(cdfA);
                const float l2o  = __builtin_amdgcn_logf(fmaxf(omuA, 1e-38f));
                const float l2p  = __builtin_amdgcn_logf(fmaxf(pdfA, 1e-38f));
                out[eA] = ((l2c - l2o) * LN2 + bA) * __builtin_amdgcn_exp2f(aA * LOG2E);
                ldj += (l2p + l2ps - l2c - l2o) * LN2 + aA;
            }
            {   // element B epilogue
                const float l2ps = __builtin_amdgcn_logf(psB);
                const float l2c  = __builtin_amdgcn_logf(cdfB);
                const float l2o  = __builtin_amdgcn_logf(fmaxf(omuB, 1e-38f));
                const float l2p  = __builtin_amdgcn_logf(fmaxf(pdfB, 1e-38f));
                out[eB] = ((l2c - l2o) * LN2 + bB) * __builtin_amdgcn_exp2f(aB * LOG2E);
                ldj += (l2p + l2ps - l2c - l2o) * LN2 + aB;
            }
        }
    }

    // ---- block reduction; block (512 elems) lies within one batch ----
    float v = ldj;
#pragma unroll
    for (int off = 32; off > 0; off >>= 1) v += __shfl_down(v, off);
    __shared__ float ws[4];
    const int w = t >> 6;
    if ((t & 63) == 0) ws[w] = v;
    __syncthreads();
    if (t == 0) {
        const float tot = ws[0] + ws[1] + ws[2] + ws[3];
        const int batch = blockIdx.x >> 6;   // 64 blocks (512 elems each) per batch
        atomicAdd(out + 2 * (size_t)NELEM + batch, tot);
    }
}

extern "C" void kernel_launch(void* const* d_in, const int* in_sizes, int n_in,
                              void* d_out, int out_size, void* d_ws, size_t ws_size,
                              hipStream_t stream) {
    const float* x_change = (const float*)d_in[0];
    const float* x_id     = (const float*)d_in[1];
    const float* sldj     = (const float*)d_in[2];
    const float* a        = (const float*)d_in[3];
    const float* b        = (const float*)d_in[4];
    const f32x4* pi       = (const f32x4*)d_in[5];
    const f32x4* mu       = (const f32x4*)d_in[6];
    const f32x4* s        = (const f32x4*)d_in[7];
    float* out = (float*)d_out;

    const int B = in_sizes[2];

    // Seed sldj output region (harness poisons d_out) with a tiny d2d copy;
    // the kernel atomically accumulates into it (stream-ordered).
    hipMemcpyAsync(out + 2 * (size_t)NELEM, sldj, B * sizeof(float),
                   hipMemcpyDeviceToDevice, stream);

    coupling_kernel<<<NBLK, 256, 0, stream>>>(x_change, x_id, a, b, pi, mu, s, out);
}